// Round 2
// baseline (148492.468 us; speedup 1.0000x reference)
//
#include <hip/hip_runtime.h>
#include <hip/hip_bf16.h>

#define B_ 32
#define S_ 512
#define E_ 256
#define H_ 512
#define T_ 8
#define G_ 2048
#define K_ 7  // T-1 tasks

__device__ __forceinline__ float sigm(float x) { return 1.f / (1.f + expf(-x)); }

__global__ void k_zero(float* p, int n) {
    int i = blockIdx.x * blockDim.x + threadIdx.x;
    if (i < n) p[i] = 0.f;
}

// emb[t][b][e] = embed[x[b][t]][e]
__global__ void k_embed(const int* __restrict__ x, const float* __restrict__ embed,
                        float* __restrict__ emb) {
    int w = blockIdx.x;           // w = t*B + b
    int t = w / B_, b = w % B_;
    int tok = x[b * S_ + t];
    emb[(size_t)w * E_ + threadIdx.x] = embed[(size_t)tok * E_ + threadIdx.x];
}

// P1T[j][i] = Ws_p1[i][j]
__global__ void k_transpose_p1(const float* __restrict__ p1, float* __restrict__ p1t) {
    int idx = blockIdx.x * 256 + threadIdx.x;  // = j*H + i
    int j = idx >> 9, i = idx & 511;
    p1t[idx] = p1[i * H_ + j];
}

// One task-LSTM step: fused gates GEMM + cell update.
// grid = K*B*4 (htile of 128), block = 256. Each thread computes 2 adjacent gate cols.
__global__ void k_task_step(const float* __restrict__ emb,
                            const float* __restrict__ h_old, float* __restrict__ h_new,
                            float* __restrict__ c,
                            const float* __restrict__ Wx_t, const float* __restrict__ Wh_t,
                            const float* __restrict__ b_t, const int* __restrict__ taskp,
                            int t) {
    __shared__ float se[E_];
    __shared__ float sh[H_];
    __shared__ float sg[512];
    int w = blockIdx.x;
    int htile = w & 3, b = (w >> 2) & 31, k = w >> 7;
    int task = *taskp;
    int kk = k < task ? k : k + 1;
    int tid = threadIdx.x;

    const float* embt = emb + ((size_t)t * B_ + b) * E_;
    const float* hrow = h_old + ((size_t)k * B_ + b) * H_;
    se[tid] = embt[tid];
    sh[tid] = hrow[tid];
    sh[tid + 256] = hrow[tid + 256];
    __syncthreads();

    // output o = 2*tid, 2*tid+1 ; gate = o/128, col-within-tile = o%128
    int o = tid * 2;
    int gate = o >> 7;
    int c1 = gate * H_ + htile * 128 + (o & 127);  // column in G=2048 gate vector
    const float* wx = Wx_t + (size_t)kk * E_ * G_ + c1;
    const float* wh = Wh_t + (size_t)kk * H_ * G_ + c1;
    float a0 = b_t[kk * G_ + c1];
    float a1 = b_t[kk * G_ + c1 + 1];
#pragma unroll 4
    for (int e = 0; e < E_; ++e) {
        float2 pw = *(const float2*)(wx + (size_t)e * G_);
        float xv = se[e];
        a0 = fmaf(xv, pw.x, a0);
        a1 = fmaf(xv, pw.y, a1);
    }
#pragma unroll 4
    for (int hh = 0; hh < H_; ++hh) {
        float2 pw = *(const float2*)(wh + (size_t)hh * G_);
        float xv = sh[hh];
        a0 = fmaf(xv, pw.x, a0);
        a1 = fmaf(xv, pw.y, a1);
    }
    sg[o] = a0;
    sg[o + 1] = a1;
    __syncthreads();
    if (tid < 128) {
        int col = htile * 128 + tid;
        size_t idx = ((size_t)k * B_ + b) * H_ + col;
        float gi = sg[tid], gf = sg[128 + tid], gg = sg[256 + tid], go = sg[384 + tid];
        float cold = c[idx];
        float cn = sigm(gf) * cold + sigm(gi) * tanhf(gg);
        float hn = sigm(go) * tanhf(cn);
        c[idx] = cn;
        h_new[idx] = hn;
    }
}

// p2[b][i] = [h_main_old | emb_t] @ Ws_p2 ; grid = B, block = 256 (2 outputs/thread)
__global__ void k_p2(const float* __restrict__ emb, const float* __restrict__ hm_old,
                     const float* __restrict__ Ws_p2, float* __restrict__ p2, int t) {
    __shared__ float cat[H_ + E_];
    int b = blockIdx.x, tid = threadIdx.x;
    cat[tid] = hm_old[b * H_ + tid];
    cat[tid + 256] = hm_old[b * H_ + tid + 256];
    cat[tid + 512] = emb[((size_t)t * B_ + b) * E_ + tid];
    __syncthreads();
    int i0 = tid * 2;
    float a0 = 0.f, a1 = 0.f;
#pragma unroll 4
    for (int j = 0; j < H_ + E_; ++j) {
        float2 pw = *(const float2*)(Ws_p2 + (size_t)j * H_ + i0);
        float xv = cat[j];
        a0 = fmaf(xv, pw.x, a0);
        a1 = fmaf(xv, pw.y, a1);
    }
    p2[b * H_ + i0] = a0;
    p2[b * H_ + i0 + 1] = a1;
}

// Si[b][k] = sum_i tanh(p2[b,i] + sum_j P1T[j,i]*h_task[k,b,j]) * Us_w[i]  + Us_b
// grid = B*K, block = 256 (2 i's per thread)
__global__ void k_attn(const float* __restrict__ h_task, const float* __restrict__ p2,
                       const float* __restrict__ p1t, const float* __restrict__ us_w,
                       const float* __restrict__ us_b, float* __restrict__ Si) {
    __shared__ float sh[H_];
    __shared__ float red[4];
    int w = blockIdx.x;
    int b = w / K_, k = w % K_;
    int tid = threadIdx.x;
    const float* hrow = h_task + ((size_t)k * B_ + b) * H_;
    sh[tid] = hrow[tid];
    sh[tid + 256] = hrow[tid + 256];
    __syncthreads();
    int i0 = tid * 2;
    float v0 = p2[b * H_ + i0], v1 = p2[b * H_ + i0 + 1];
#pragma unroll 4
    for (int j = 0; j < H_; ++j) {
        float hj = sh[j];
        float2 pp = *(const float2*)(p1t + (size_t)j * H_ + i0);
        v0 = fmaf(pp.x, hj, v0);
        v1 = fmaf(pp.y, hj, v1);
    }
    float s = tanhf(v0) * us_w[i0] + tanhf(v1) * us_w[i0 + 1];
    for (int off = 32; off > 0; off >>= 1) s += __shfl_down(s, off, 64);
    if ((tid & 63) == 0) red[tid >> 6] = s;
    __syncthreads();
    if (tid == 0) Si[b * K_ + k] = red[0] + red[1] + red[2] + red[3] + us_b[0];
}

// Main LSTM step: softmax+Rt (recomputed per wg), fused gates GEMM + cell + out write.
// grid = B*4 (htile of 128), block = 256.
__global__ void k_main_step(const float* __restrict__ emb, const float* __restrict__ h_task,
                            const float* __restrict__ hm_old, float* __restrict__ hm_new,
                            float* __restrict__ cm, const float* __restrict__ Si,
                            const float* __restrict__ Wx_c, const float* __restrict__ Wh_c,
                            const float* __restrict__ Wm_c, const float* __restrict__ b_c,
                            float* __restrict__ out, int t) {
    __shared__ float se[E_];
    __shared__ float shm[H_];
    __shared__ float srt[H_];
    __shared__ float sg[512];
    int w = blockIdx.x;
    int htile = w & 3, b = w >> 2;
    int tid = threadIdx.x;
    se[tid] = emb[((size_t)t * B_ + b) * E_ + tid];
    shm[tid] = hm_old[b * H_ + tid];
    shm[tid + 256] = hm_old[b * H_ + tid + 256];

    // softmax over the 7 task scores (each thread redundantly)
    float a[K_];
    float m = -1e30f;
    for (int k = 0; k < K_; ++k) { a[k] = Si[b * K_ + k]; m = fmaxf(m, a[k]); }
    float den = 0.f;
    for (int k = 0; k < K_; ++k) { a[k] = expf(a[k] - m); den += a[k]; }
    float rden = 1.f / den;
    float r0 = 0.f, r1 = 0.f;
    for (int k = 0; k < K_; ++k) {
        const float* hr = h_task + ((size_t)k * B_ + b) * H_;
        r0 = fmaf(a[k], hr[tid], r0);
        r1 = fmaf(a[k], hr[tid + 256], r1);
    }
    srt[tid] = r0 * rden;
    srt[tid + 256] = r1 * rden;
    __syncthreads();

    int o = tid * 2;
    int gate = o >> 7;
    int c1 = gate * H_ + htile * 128 + (o & 127);
    float a0 = b_c[c1], a1 = b_c[c1 + 1];
    const float* wx = Wx_c + c1;
    const float* wh = Wh_c + c1;
    const float* wm = Wm_c + c1;
#pragma unroll 4
    for (int e = 0; e < E_; ++e) {
        float2 pw = *(const float2*)(wx + (size_t)e * G_);
        float xv = se[e];
        a0 = fmaf(xv, pw.x, a0);
        a1 = fmaf(xv, pw.y, a1);
    }
#pragma unroll 4
    for (int hh = 0; hh < H_; ++hh) {
        float2 pw = *(const float2*)(wh + (size_t)hh * G_);
        float xv = shm[hh];
        a0 = fmaf(xv, pw.x, a0);
        a1 = fmaf(xv, pw.y, a1);
    }
#pragma unroll 4
    for (int hh = 0; hh < H_; ++hh) {
        float2 pw = *(const float2*)(wm + (size_t)hh * G_);
        float xv = srt[hh];
        a0 = fmaf(xv, pw.x, a0);
        a1 = fmaf(xv, pw.y, a1);
    }
    sg[o] = a0;
    sg[o + 1] = a1;
    __syncthreads();
    if (tid < 128) {
        int col = htile * 128 + tid;
        size_t idx = (size_t)b * H_ + col;
        float gi = sg[tid], gf = sg[128 + tid], gg = sg[256 + tid], go = sg[384 + tid];
        float cold = cm[idx];
        float cn = sigm(gf) * cold + sigm(gi) * tanhf(gg);
        float hn = sigm(go) * tanhf(cn);
        cm[idx] = cn;
        hm_new[idx] = hn;
        out[(size_t)b * S_ * H_ + (size_t)t * H_ + col] = hn;
    }
}

__global__ void k_copy_hn(const float* __restrict__ hm, float* __restrict__ out) {
    int i = blockIdx.x * 256 + threadIdx.x;
    out[(size_t)B_ * S_ * H_ + i] = hm[i];
}

extern "C" void kernel_launch(void* const* d_in, const int* in_sizes, int n_in,
                              void* d_out, int out_size, void* d_ws, size_t ws_size,
                              hipStream_t stream) {
    const int*   x      = (const int*)d_in[0];
    const int*   taskp  = (const int*)d_in[1];
    const float* embed  = (const float*)d_in[2];
    const float* Wx_t   = (const float*)d_in[3];
    const float* Wh_t   = (const float*)d_in[4];
    const float* b_t    = (const float*)d_in[5];
    const float* Ws_p1  = (const float*)d_in[6];
    const float* Ws_p2  = (const float*)d_in[7];
    const float* Us_w   = (const float*)d_in[8];
    const float* Us_b   = (const float*)d_in[9];
    const float* Wx_c   = (const float*)d_in[10];
    const float* Wh_c   = (const float*)d_in[11];
    const float* Wm_c   = (const float*)d_in[12];
    const float* b_c    = (const float*)d_in[13];
    float* out = (float*)d_out;

    float* ws = (float*)d_ws;
    float* emb    = ws;                                  // S*B*E   = 4,194,304
    float* p1t    = emb    + (size_t)S_ * B_ * E_;       // H*H     =   262,144
    float* h_task = p1t    + (size_t)H_ * H_;            // 2*K*B*H =   229,376
    float* c_task = h_task + 2 * (size_t)K_ * B_ * H_;   // K*B*H   =   114,688
    float* h_main = c_task + (size_t)K_ * B_ * H_;       // 2*B*H   =    32,768
    float* c_main = h_main + 2 * (size_t)B_ * H_;        // B*H     =    16,384
    float* p2     = c_main + (size_t)B_ * H_;            // B*H     =    16,384
    float* Si     = p2     + (size_t)B_ * H_;            // 256

    // zero the recurrent state (h_task..c_main are contiguous)
    int nzero = 2 * K_ * B_ * H_ + K_ * B_ * H_ + 2 * B_ * H_ + B_ * H_;
    k_zero<<<(nzero + 255) / 256, 256, 0, stream>>>(h_task, nzero);
    k_embed<<<S_ * B_, 256, 0, stream>>>(x, embed, emb);
    k_transpose_p1<<<H_ * H_ / 256, 256, 0, stream>>>(Ws_p1, p1t);

    for (int t = 0; t < S_; ++t) {
        int old = t & 1, nw = old ^ 1;
        float* ht_old = h_task + (size_t)old * K_ * B_ * H_;
        float* ht_new = h_task + (size_t)nw * K_ * B_ * H_;
        float* hm_old = h_main + (size_t)old * B_ * H_;
        float* hm_new = h_main + (size_t)nw * B_ * H_;
        k_task_step<<<K_ * B_ * 4, 256, 0, stream>>>(emb, ht_old, ht_new, c_task,
                                                     Wx_t, Wh_t, b_t, taskp, t);
        k_p2<<<B_, 256, 0, stream>>>(emb, hm_old, Ws_p2, p2, t);
        k_attn<<<B_ * K_, 256, 0, stream>>>(ht_new, p2, p1t, Us_w, Us_b, Si);
        k_main_step<<<B_ * 4, 256, 0, stream>>>(emb, ht_new, hm_old, hm_new, c_main, Si,
                                                Wx_c, Wh_c, Wm_c, b_c, out, t);
    }
    // final h is in buffer 0 after 512 steps
    k_copy_hn<<<B_ * H_ / 256, 256, 0, stream>>>(h_main, out);
}

// Round 3
// 66758.588 us; speedup vs baseline: 2.2243x; 2.2243x over previous
//
#include <hip/hip_runtime.h>
#include <hip/hip_bf16.h>

#define B_ 32
#define S_ 512
#define E_ 256
#define H_ 512
#define G_ 2048
#define K_ 7   // T-1 tasks
#define PAD 36   // act_t row stride (floats): 144B rows keep b128 alignment
#define PADC 12  // kernel C act_t row stride (8 batches)

__device__ __forceinline__ float sigm(float x) { return 1.f / (1.f + expf(-x)); }

__global__ void k_zero(float* p, int n) {
    int i = blockIdx.x * blockDim.x + threadIdx.x;
    if (i < n) p[i] = 0.f;
}

__global__ void k_embed(const int* __restrict__ x, const float* __restrict__ embed,
                        float* __restrict__ emb) {
    int w = blockIdx.x;           // w = ts*B + b
    int ts = w / B_, b = w % B_;
    int tok = x[b * S_ + ts];
    emb[(size_t)w * E_ + threadIdx.x] = embed[(size_t)tok * E_ + threadIdx.x];
}

// P1T[j][i] = Ws_p1[i][j]
__global__ void k_transpose_p1(const float* __restrict__ p1, float* __restrict__ p1t) {
    int idx = blockIdx.x * 256 + threadIdx.x;  // = j*H + i
    int j = idx >> 9, i = idx & 511;
    p1t[idx] = p1[i * H_ + j];
}

// ---------------- Phase A: task LSTM gates+cell (blocks 0..223) + p2 GEMM (224..231)
// Task block (k, nt): all 32 batches, 64 gate-cols (4 gates x 16 h-cols), K = 256+512.
// Thread: c = tid&31 -> cols 2c,2c+1 ; bg = tid>>5 -> batches 4bg..4bg+3.
__global__ __launch_bounds__(256) void k_phase_a(
        const float* __restrict__ emb, const float* __restrict__ h_old,
        float* __restrict__ h_new, float* __restrict__ c_task,
        const float* __restrict__ Wx_t, const float* __restrict__ Wh_t,
        const float* __restrict__ b_t, const int* __restrict__ taskp,
        const float* __restrict__ hm_old, const float* __restrict__ Ws_p2,
        float* __restrict__ p2, int ts) {
    __shared__ float act[512 * PAD];
    __shared__ float sg[32 * 64];
    int blk = blockIdx.x, tid = threadIdx.x;
    int c = tid & 31, bg = tid >> 5;
    int l0 = 2 * c;

    if (blk < 224) {
        int k = blk >> 5, nt = blk & 31;
        int task = *taskp;
        int kk = k + (k >= task);
        int gate = l0 >> 4, off = l0 & 15;
        int wc = gate * 512 + nt * 16 + off;

        float acc0[4], acc1[4];
        float bi0 = b_t[kk * G_ + wc], bi1 = b_t[kk * G_ + wc + 1];
#pragma unroll
        for (int j = 0; j < 4; ++j) { acc0[j] = bi0; acc1[j] = bi1; }

        // part 1: emb (256 rows) x Wx_t[kk]
        for (int idx = tid; idx < 256 * 32; idx += 256) {
            int r = idx & 255, b = idx >> 8;
            act[r * PAD + b] = emb[((size_t)ts * B_ + b) * E_ + r];
        }
        __syncthreads();
        const float* W = Wx_t + (size_t)kk * E_ * G_;
        for (int r = 0; r < 256; ++r) {
            float2 w = *(const float2*)(W + (size_t)r * G_ + wc);
            float4 av = *(const float4*)(act + r * PAD + 4 * bg);
            acc0[0] = fmaf(w.x, av.x, acc0[0]); acc1[0] = fmaf(w.y, av.x, acc1[0]);
            acc0[1] = fmaf(w.x, av.y, acc0[1]); acc1[1] = fmaf(w.y, av.y, acc1[1]);
            acc0[2] = fmaf(w.x, av.z, acc0[2]); acc1[2] = fmaf(w.y, av.z, acc1[2]);
            acc0[3] = fmaf(w.x, av.w, acc0[3]); acc1[3] = fmaf(w.y, av.w, acc1[3]);
        }
        __syncthreads();
        // part 2: h_old[k] (512 rows) x Wh_t[kk]
        for (int idx = tid; idx < 512 * 32; idx += 256) {
            int r = idx & 511, b = idx >> 9;
            act[r * PAD + b] = h_old[((size_t)k * B_ + b) * H_ + r];
        }
        __syncthreads();
        W = Wh_t + (size_t)kk * H_ * G_;
        for (int r = 0; r < 512; ++r) {
            float2 w = *(const float2*)(W + (size_t)r * G_ + wc);
            float4 av = *(const float4*)(act + r * PAD + 4 * bg);
            acc0[0] = fmaf(w.x, av.x, acc0[0]); acc1[0] = fmaf(w.y, av.x, acc1[0]);
            acc0[1] = fmaf(w.x, av.y, acc0[1]); acc1[1] = fmaf(w.y, av.y, acc1[1]);
            acc0[2] = fmaf(w.x, av.z, acc0[2]); acc1[2] = fmaf(w.y, av.z, acc1[2]);
            acc0[3] = fmaf(w.x, av.w, acc0[3]); acc1[3] = fmaf(w.y, av.w, acc1[3]);
        }
#pragma unroll
        for (int j = 0; j < 4; ++j) {
            sg[(4 * bg + j) * 64 + l0] = acc0[j];
            sg[(4 * bg + j) * 64 + l0 + 1] = acc1[j];
        }
        __syncthreads();
        // cell update: 512 cells = 32 b x 16 hc
        for (int cell = tid; cell < 512; cell += 256) {
            int hc = cell & 15, b = cell >> 4;
            float gi = sg[b * 64 + hc], gf = sg[b * 64 + 16 + hc];
            float gg = sg[b * 64 + 32 + hc], go = sg[b * 64 + 48 + hc];
            size_t cidx = ((size_t)k * B_ + b) * H_ + nt * 16 + hc;
            float cold = c_task[cidx];
            float cn = sigm(gf) * cold + sigm(gi) * tanhf(gg);
            float hn = sigm(go) * tanhf(cn);
            c_task[cidx] = cn;
            h_new[cidx] = hn;
        }
    } else {
        // p2 block: pb in 0..7, i-cols [pb*64, +64). p2 = [hm_old | emb] @ Ws_p2
        int pb = blk - 224;
        int wc = pb * 64 + l0;
        float acc0[4], acc1[4];
#pragma unroll
        for (int j = 0; j < 4; ++j) { acc0[j] = 0.f; acc1[j] = 0.f; }
        // part 1: hm_old (rows 0..511 of Ws_p2)
        for (int idx = tid; idx < 512 * 32; idx += 256) {
            int r = idx & 511, b = idx >> 9;
            act[r * PAD + b] = hm_old[(size_t)b * H_ + r];
        }
        __syncthreads();
        for (int r = 0; r < 512; ++r) {
            float2 w = *(const float2*)(Ws_p2 + (size_t)r * H_ + wc);
            float4 av = *(const float4*)(act + r * PAD + 4 * bg);
            acc0[0] = fmaf(w.x, av.x, acc0[0]); acc1[0] = fmaf(w.y, av.x, acc1[0]);
            acc0[1] = fmaf(w.x, av.y, acc0[1]); acc1[1] = fmaf(w.y, av.y, acc1[1]);
            acc0[2] = fmaf(w.x, av.z, acc0[2]); acc1[2] = fmaf(w.y, av.z, acc1[2]);
            acc0[3] = fmaf(w.x, av.w, acc0[3]); acc1[3] = fmaf(w.y, av.w, acc1[3]);
        }
        __syncthreads();
        // part 2: emb (rows 512..767 of Ws_p2)
        for (int idx = tid; idx < 256 * 32; idx += 256) {
            int r = idx & 255, b = idx >> 8;
            act[r * PAD + b] = emb[((size_t)ts * B_ + b) * E_ + r];
        }
        __syncthreads();
        for (int r = 0; r < 256; ++r) {
            float2 w = *(const float2*)(Ws_p2 + (size_t)(512 + r) * H_ + wc);
            float4 av = *(const float4*)(act + r * PAD + 4 * bg);
            acc0[0] = fmaf(w.x, av.x, acc0[0]); acc1[0] = fmaf(w.y, av.x, acc1[0]);
            acc0[1] = fmaf(w.x, av.y, acc0[1]); acc1[1] = fmaf(w.y, av.y, acc1[1]);
            acc0[2] = fmaf(w.x, av.z, acc0[2]); acc1[2] = fmaf(w.y, av.z, acc1[2]);
            acc0[3] = fmaf(w.x, av.w, acc0[3]); acc1[3] = fmaf(w.y, av.w, acc1[3]);
        }
#pragma unroll
        for (int j = 0; j < 4; ++j) {
            p2[(size_t)(4 * bg + j) * H_ + wc] = acc0[j];
            p2[(size_t)(4 * bg + j) * H_ + wc + 1] = acc1[j];
        }
    }
}

// ---------------- Phase B: attention score partials.
// Block (k, it): i-cols [it*16,+16), all 32 b, K=512 over h_task[k].
// partial[k][it][b] = sum_{i in tile} tanh(p1row + p2) * usw[i]
__global__ __launch_bounds__(256) void k_phase_b(
        const float* __restrict__ h_new, const float* __restrict__ p2,
        const float* __restrict__ p1t, const float* __restrict__ usw,
        float* __restrict__ partial) {
    __shared__ float act[512 * PAD];
    int blk = blockIdx.x, tid = threadIdx.x;
    int k = blk >> 5, it = blk & 31;
    int ci = tid & 15, bg = tid >> 4;  // i-col within tile; 2 batches: 2bg, 2bg+1

    for (int idx = tid; idx < 512 * 32; idx += 256) {
        int r = idx & 511, b = idx >> 9;
        act[r * PAD + b] = h_new[((size_t)k * B_ + b) * H_ + r];
    }
    __syncthreads();

    int icol = it * 16 + ci;
    float a0 = 0.f, a1 = 0.f;
    for (int r = 0; r < 512; ++r) {
        float w = p1t[(size_t)r * H_ + icol];
        float2 av = *(const float2*)(act + r * PAD + 2 * bg);
        a0 = fmaf(w, av.x, a0);
        a1 = fmaf(w, av.y, a1);
    }
    float uw = usw[icol];
    float s0 = tanhf(a0 + p2[(size_t)(2 * bg) * H_ + icol]) * uw;
    float s1 = tanhf(a1 + p2[(size_t)(2 * bg + 1) * H_ + icol]) * uw;
#pragma unroll
    for (int m = 1; m < 16; m <<= 1) {
        s0 += __shfl_xor(s0, m, 64);
        s1 += __shfl_xor(s1, m, 64);
    }
    if (ci == 0) {
        partial[((size_t)k * 32 + it) * 32 + 2 * bg] = s0;
        partial[((size_t)k * 32 + it) * 32 + 2 * bg + 1] = s1;
    }
}

// ---------------- Phase C: softmax + Rt + main gates GEMM + cell + out.
// Block (bt, nt): 8 batches (8bt..), 64 gate-cols (4 gates x 16 hc). K = 256+512+512.
// Thread: c = tid&31 -> cols 2c,2c+1 ; bg = tid>>5 -> batch 8bt+bg.
__global__ __launch_bounds__(256) void k_phase_c(
        const float* __restrict__ emb, const float* __restrict__ h_new,
        const float* __restrict__ hm_old, float* __restrict__ hm_new,
        float* __restrict__ c_main, const float* __restrict__ partial,
        const float* __restrict__ Wx_c, const float* __restrict__ Wh_c,
        const float* __restrict__ Wm_c, const float* __restrict__ b_c,
        float* __restrict__ out, int ts) {
    __shared__ float act[512 * PADC];
    __shared__ float ssi[8][K_];
    __shared__ float sa[8][K_];
    __shared__ float sg[8 * 64];
    int blk = blockIdx.x, tid = threadIdx.x;
    int bt = blk >> 5, nt = blk & 31;
    int c = tid & 31, bg = tid >> 5;
    int l0 = 2 * c;
    int gate = l0 >> 4, off = l0 & 15;
    int wc = gate * 512 + nt * 16 + off;

    // Si sums (redundant per block, tiny)
    if (tid < 8 * K_) {
        int k = tid % K_, bl = tid / K_;
        float s = 0.f;
        for (int it = 0; it < 32; ++it)
            s += partial[((size_t)k * 32 + it) * 32 + 8 * bt + bl];
        ssi[bl][k] = s;
    }
    __syncthreads();
    if (tid < 8) {
        float m = -1e30f;
        for (int k = 0; k < K_; ++k) m = fmaxf(m, ssi[tid][k]);
        float den = 0.f, e[K_];
        for (int k = 0; k < K_; ++k) { e[k] = expf(ssi[tid][k] - m); den += e[k]; }
        float rd = 1.f / den;
        for (int k = 0; k < K_; ++k) sa[tid][k] = e[k] * rd;
    }
    __syncthreads();

    float acc0 = b_c[wc], acc1 = b_c[wc + 1];

    // part 1: emb x Wx_c (256 rows)
    for (int idx = tid; idx < 256 * 8; idx += 256) {
        int r = idx & 255, bl = idx >> 8;
        act[r * PADC + bl] = emb[((size_t)ts * B_ + 8 * bt + bl) * E_ + r];
    }
    __syncthreads();
    for (int r = 0; r < 256; ++r) {
        float2 w = *(const float2*)(Wx_c + (size_t)r * G_ + wc);
        float a = act[r * PADC + bg];
        acc0 = fmaf(w.x, a, acc0);
        acc1 = fmaf(w.y, a, acc1);
    }
    __syncthreads();
    // part 2: hm_old x Wh_c (512 rows)
    for (int idx = tid; idx < 512 * 8; idx += 256) {
        int r = idx & 511, bl = idx >> 9;
        act[r * PADC + bl] = hm_old[(size_t)(8 * bt + bl) * H_ + r];
    }
    __syncthreads();
    for (int r = 0; r < 512; ++r) {
        float2 w = *(const float2*)(Wh_c + (size_t)r * G_ + wc);
        float a = act[r * PADC + bg];
        acc0 = fmaf(w.x, a, acc0);
        acc1 = fmaf(w.y, a, acc1);
    }
    __syncthreads();
    // part 3: Rt x Wm_c (512 rows); Rt built from h_task + softmax weights
    for (int idx = tid; idx < 512 * 8; idx += 256) {
        int r = idx & 511, bl = idx >> 9;
        float v = 0.f;
#pragma unroll
        for (int k = 0; k < K_; ++k)
            v = fmaf(sa[bl][k], h_new[((size_t)k * B_ + 8 * bt + bl) * H_ + r], v);
        act[r * PADC + bl] = v;
    }
    __syncthreads();
    for (int r = 0; r < 512; ++r) {
        float2 w = *(const float2*)(Wm_c + (size_t)r * G_ + wc);
        float a = act[r * PADC + bg];
        acc0 = fmaf(w.x, a, acc0);
        acc1 = fmaf(w.y, a, acc1);
    }

    sg[bg * 64 + l0] = acc0;
    sg[bg * 64 + l0 + 1] = acc1;
    __syncthreads();
    // cell: 128 cells = 8 b x 16 hc
    if (tid < 128) {
        int hc = tid & 15, bl = tid >> 4;
        int b = 8 * bt + bl;
        float gi = sg[bl * 64 + hc], gf = sg[bl * 64 + 16 + hc];
        float gg = sg[bl * 64 + 32 + hc], go = sg[bl * 64 + 48 + hc];
        size_t cidx = (size_t)b * H_ + nt * 16 + hc;
        float cold = c_main[cidx];
        float cn = sigm(gf) * cold + sigm(gi) * tanhf(gg);
        float hn = sigm(go) * tanhf(cn);
        c_main[cidx] = cn;
        hm_new[cidx] = hn;
        out[(size_t)b * S_ * H_ + (size_t)ts * H_ + nt * 16 + hc] = hn;
    }
}

__global__ void k_copy_hn(const float* __restrict__ hm, float* __restrict__ out) {
    int i = blockIdx.x * 256 + threadIdx.x;
    out[(size_t)B_ * S_ * H_ + i] = hm[i];
}

extern "C" void kernel_launch(void* const* d_in, const int* in_sizes, int n_in,
                              void* d_out, int out_size, void* d_ws, size_t ws_size,
                              hipStream_t stream) {
    const int*   x      = (const int*)d_in[0];
    const int*   taskp  = (const int*)d_in[1];
    const float* embed  = (const float*)d_in[2];
    const float* Wx_t   = (const float*)d_in[3];
    const float* Wh_t   = (const float*)d_in[4];
    const float* b_t    = (const float*)d_in[5];
    const float* Ws_p1  = (const float*)d_in[6];
    const float* Ws_p2  = (const float*)d_in[7];
    const float* Us_w   = (const float*)d_in[8];
    const float* Wx_c   = (const float*)d_in[10];
    const float* Wh_c   = (const float*)d_in[11];
    const float* Wm_c   = (const float*)d_in[12];
    const float* b_c    = (const float*)d_in[13];
    float* out = (float*)d_out;

    float* ws = (float*)d_ws;
    float* emb     = ws;                                  // S*B*E   = 4,194,304
    float* p1t     = emb     + (size_t)S_ * B_ * E_;      // H*H     =   262,144
    float* h_task  = p1t     + (size_t)H_ * H_;           // 2*K*B*H =   229,376
    float* c_task  = h_task  + 2 * (size_t)K_ * B_ * H_;  // K*B*H   =   114,688
    float* h_main  = c_task  + (size_t)K_ * B_ * H_;      // 2*B*H   =    32,768
    float* c_main  = h_main  + 2 * (size_t)B_ * H_;       // B*H     =    16,384
    float* p2      = c_main  + (size_t)B_ * H_;           // B*H     =    16,384
    float* partial = p2      + (size_t)B_ * H_;           // K*32*32 =     7,168

    int nzero = 2 * K_ * B_ * H_ + K_ * B_ * H_ + 2 * B_ * H_ + B_ * H_;
    k_zero<<<(nzero + 255) / 256, 256, 0, stream>>>(h_task, nzero);
    k_embed<<<S_ * B_, 256, 0, stream>>>(x, embed, emb);
    k_transpose_p1<<<H_ * H_ / 256, 256, 0, stream>>>(Ws_p1, p1t);

    for (int t = 0; t < S_; ++t) {
        int old = t & 1, nw = old ^ 1;
        float* ht_old = h_task + (size_t)old * K_ * B_ * H_;
        float* ht_new = h_task + (size_t)nw * K_ * B_ * H_;
        float* hm_old = h_main + (size_t)old * B_ * H_;
        float* hm_new = h_main + (size_t)nw * B_ * H_;
        k_phase_a<<<232, 256, 0, stream>>>(emb, ht_old, ht_new, c_task,
                                           Wx_t, Wh_t, b_t, taskp,
                                           hm_old, Ws_p2, p2, t);
        k_phase_b<<<224, 256, 0, stream>>>(ht_new, p2, p1t, Us_w, partial);
        k_phase_c<<<128, 256, 0, stream>>>(emb, ht_new, hm_old, hm_new, c_main,
                                           partial, Wx_c, Wh_c, Wm_c, b_c, out, t);
    }
    k_copy_hn<<<B_ * H_ / 256, 256, 0, stream>>>(h_main, out);
}

// Round 5
// 63578.351 us; speedup vs baseline: 2.3356x; 1.0500x over previous
//
#include <hip/hip_runtime.h>
#include <hip/hip_bf16.h>

#define B_ 32
#define S_ 512
#define E_ 256
#define H_ 512
#define G_ 2048
#define K_ 7     // T-1 tasks
#define PAD 36   // phase A transposed act row stride (floats)
#define PADB 513 // phase B row-major act stride (floats) -> conflict-free
#define PADC 9   // phase C transposed act row stride -> conflict-free staging

__device__ __forceinline__ float sigm(float x) { return 1.f / (1.f + expf(-x)); }

__global__ void k_zero(float* p, int n) {
    int i = blockIdx.x * blockDim.x + threadIdx.x;
    if (i < n) p[i] = 0.f;
}

__global__ void k_embed(const int* __restrict__ x, const float* __restrict__ embed,
                        float* __restrict__ emb) {
    int w = blockIdx.x;           // w = ts*B + b
    int ts = w / B_, b = w % B_;
    int tok = x[b * S_ + ts];
    emb[(size_t)w * E_ + threadIdx.x] = embed[(size_t)tok * E_ + threadIdx.x];
}

// P1T[j][i] = Ws_p1[i][j]
__global__ void k_transpose_p1(const float* __restrict__ p1, float* __restrict__ p1t) {
    int idx = blockIdx.x * 256 + threadIdx.x;  // = j*H + i
    int j = idx >> 9, i = idx & 511;
    p1t[idx] = p1[i * H_ + j];
}

// 64-row x 64-col weight tile: load to regs (4 float4/thread), park to LDS.
// Wcol = per-thread column-adjusted base pointer; ld = row stride.
__device__ __forceinline__ void ld_tile64(const float* Wcol, size_t ld, int r0, int rr,
                                          float4 R[4]) {
    const float* g = Wcol + (size_t)(r0 + rr) * ld;
#pragma unroll
    for (int j = 0; j < 4; ++j) R[j] = *(const float4*)(g + (size_t)(16 * j) * ld);
}
__device__ __forceinline__ void st_tile64(float* buf, int rr, int cc, const float4 R[4]) {
#pragma unroll
    for (int j = 0; j < 4; ++j) *(float4*)(buf + (16 * j + rr) * 64 + cc) = R[j];
}

// ---------------- Phase A: task LSTM gates+cell (blocks 0..223) + p2 GEMM (224..231)
// Task block (k, nt): 32 batches x 64 gate-cols, K = 256 (emb) + 512 (h).
// Thread: c=tid&31 -> col pair, bg=tid>>5 -> 4 batches. 8 FMA/row.
__global__ __launch_bounds__(256) void k_phase_a(
        const float* __restrict__ emb, const float* __restrict__ h_old,
        float* __restrict__ h_new, float* __restrict__ c_task,
        const float* __restrict__ Wx_t, const float* __restrict__ Wh_t,
        const float* __restrict__ b_t, const int* __restrict__ taskp,
        const float* __restrict__ hm_old, const float* __restrict__ Ws_p2,
        float* __restrict__ p2, int ts) {
    __shared__ float sact[512 * PAD];     // 73,728 B
    __shared__ float swt[2][64 * 64];     // 32,768 B
    __shared__ float sg[32 * 64];         //  8,192 B
    int blk = blockIdx.x, tid = threadIdx.x;
    int c = tid & 31, bg = tid >> 5;
    int l0 = 2 * c;
    int rr = tid >> 4;                    // tile row 0..15 (loader)
    int cc = (tid & 15) << 2;             // tile col 0,4..60 (loader)

    bool is_task = blk < 224;
    int k = 0, nt = 0, pb = 0, kk = 0, wc;
    const float* Wbase[2];
    const float* b0;
    int nrows[2];
    if (is_task) {
        k = blk >> 5; nt = blk & 31;
        int task = *taskp;
        kk = k + (k >= task);
        wc = (l0 >> 4) * 512 + nt * 16 + (l0 & 15);
        int gcol = (cc >> 4) * 512 + nt * 16 + (cc & 15);
        Wbase[0] = Wx_t + (size_t)kk * E_ * G_ + gcol;
        Wbase[1] = Wh_t + (size_t)kk * H_ * G_ + gcol;
        nrows[0] = 256; nrows[1] = 512;
        b0 = b_t + kk * G_;
    } else {
        pb = blk - 224;
        wc = pb * 64 + l0;
        int gcol = pb * 64 + cc;
        Wbase[0] = Ws_p2 + gcol;                    // rows 0..511: hm_old
        Wbase[1] = Ws_p2 + (size_t)512 * H_ + gcol; // rows 512..767: emb
        nrows[0] = 512; nrows[1] = 256;
        b0 = nullptr;
    }
    size_t ld = is_task ? G_ : H_;

    float acc0[4], acc1[4];
    float bi0 = is_task ? b0[wc] : 0.f;
    float bi1 = is_task ? b0[wc + 1] : 0.f;
#pragma unroll
    for (int j = 0; j < 4; ++j) { acc0[j] = bi0; acc1[j] = bi1; }

    float4 R[4];
    for (int part = 0; part < 2; ++part) {
        // stage activations (transposed [r][b]) for this part
        if (is_task) {
            if (part == 0) {
                for (int idx = tid; idx < 256 * 32; idx += 256) {
                    int r = idx & 255, b = idx >> 8;
                    sact[r * PAD + b] = emb[((size_t)ts * B_ + b) * E_ + r];
                }
            } else {
                for (int idx = tid; idx < 512 * 32; idx += 256) {
                    int r = idx & 511, b = idx >> 9;
                    sact[r * PAD + b] = h_old[((size_t)k * B_ + b) * H_ + r];
                }
            }
        } else {
            if (part == 0) {
                for (int idx = tid; idx < 512 * 32; idx += 256) {
                    int r = idx & 511, b = idx >> 9;
                    sact[r * PAD + b] = hm_old[(size_t)b * H_ + r];
                }
            } else {
                for (int idx = tid; idx < 256 * 32; idx += 256) {
                    int r = idx & 255, b = idx >> 8;
                    sact[r * PAD + b] = emb[((size_t)ts * B_ + b) * E_ + r];
                }
            }
        }
        const float* W = Wbase[part];
        int NC = nrows[part] >> 6;
        ld_tile64(W, ld, 0, rr, R);
        __syncthreads();               // prev part compute done; sact writes above precede
        st_tile64(swt[0], rr, cc, R);
        if (NC > 1) ld_tile64(W, ld, 64, rr, R);
        __syncthreads();               // sact + swt[0] visible
        int cur = 0;
        for (int ch = 0; ch < NC; ++ch) {
            const float* wb = swt[cur];
            const float* ab = sact + (size_t)(ch * 64) * PAD + 4 * bg;
#pragma unroll 8
            for (int r = 0; r < 64; ++r) {
                float2 w = *(const float2*)(wb + r * 64 + l0);
                float4 av = *(const float4*)(ab + r * PAD);
                acc0[0] = fmaf(w.x, av.x, acc0[0]); acc1[0] = fmaf(w.y, av.x, acc1[0]);
                acc0[1] = fmaf(w.x, av.y, acc0[1]); acc1[1] = fmaf(w.y, av.y, acc1[1]);
                acc0[2] = fmaf(w.x, av.z, acc0[2]); acc1[2] = fmaf(w.y, av.z, acc1[2]);
                acc0[3] = fmaf(w.x, av.w, acc0[3]); acc1[3] = fmaf(w.y, av.w, acc1[3]);
            }
            __syncthreads();
            if (ch + 1 < NC) {
                st_tile64(swt[cur ^ 1], rr, cc, R);
                if (ch + 2 < NC) ld_tile64(W, ld, (ch + 2) * 64, rr, R);
                __syncthreads();
                cur ^= 1;
            }
        }
    }

    if (is_task) {
#pragma unroll
        for (int j = 0; j < 4; ++j) {
            sg[(4 * bg + j) * 64 + l0] = acc0[j];
            sg[(4 * bg + j) * 64 + l0 + 1] = acc1[j];
        }
        __syncthreads();
        for (int cell = tid; cell < 512; cell += 256) {
            int hc = cell & 15, b = cell >> 4;
            float gi = sg[b * 64 + hc], gf = sg[b * 64 + 16 + hc];
            float gg = sg[b * 64 + 32 + hc], go = sg[b * 64 + 48 + hc];
            size_t cidx = ((size_t)k * B_ + b) * H_ + nt * 16 + hc;
            float cold = c_task[cidx];
            float cn = sigm(gf) * cold + sigm(gi) * tanhf(gg);
            float hn = sigm(go) * tanhf(cn);
            c_task[cidx] = cn;
            h_new[cidx] = hn;
        }
    } else {
#pragma unroll
        for (int j = 0; j < 4; ++j) {
            p2[(size_t)(4 * bg + j) * H_ + wc] = acc0[j];
            p2[(size_t)(4 * bg + j) * H_ + wc + 1] = acc1[j];
        }
    }
}

// ---------------- Phase B: attention score partials.
// Block (k, it): i-cols [it*16,+16), 32 batches, K=512 over h_new[k].
__global__ __launch_bounds__(256) void k_phase_b(
        const float* __restrict__ h_new, const float* __restrict__ p2,
        const float* __restrict__ p1t, const float* __restrict__ usw,
        float* __restrict__ partial) {
    __shared__ float sact[32 * PADB];     // 65,664 B, row-major [b][r]
    __shared__ float swt[2][64 * 16];     //  8,192 B
    int blk = blockIdx.x, tid = threadIdx.x;
    int kt = blk >> 5, it = blk & 31;
    int ci = tid & 15, bgp = tid >> 4;    // i-col; batch pair 2bgp,2bgp+1

    // stage h (row-major, float4 global, scalar LDS writes conflict-free)
    for (int idx = tid; idx < 512 * 32 / 4; idx += 256) {
        int b = idx >> 7, j4 = (idx & 127) << 2;
        float4 v = *(const float4*)(h_new + ((size_t)kt * B_ + b) * H_ + j4);
        float* d = sact + b * PADB + j4;
        d[0] = v.x; d[1] = v.y; d[2] = v.z; d[3] = v.w;
    }
    // p1t tile loader: rr2=tid>>2 (0..63), cc2=(tid&3)*4
    int rr2 = tid >> 2, cc2 = (tid & 3) << 2;
    const float* Wcol = p1t + it * 16 + cc2;
    float4 R;
    R = *(const float4*)(Wcol + (size_t)rr2 * H_);
    __syncthreads();
    *(float4*)(swt[0] + rr2 * 16 + cc2) = R;
    R = *(const float4*)(Wcol + (size_t)(64 + rr2) * H_);
    __syncthreads();

    const float* h0 = sact + (2 * bgp) * PADB;
    const float* h1 = sact + (2 * bgp + 1) * PADB;
    float a0 = 0.f, a1 = 0.f;
    int cur = 0;
    for (int ch = 0; ch < 8; ++ch) {
        const float* wb = swt[cur] + ci;
        int r0 = ch * 64;
#pragma unroll 8
        for (int r = 0; r < 64; ++r) {
            float w = wb[r * 16];
            a0 = fmaf(w, h0[r0 + r], a0);
            a1 = fmaf(w, h1[r0 + r], a1);
        }
        __syncthreads();
        if (ch + 1 < 8) {
            *(float4*)(swt[cur ^ 1] + rr2 * 16 + cc2) = R;
            if (ch + 2 < 8) R = *(const float4*)(Wcol + (size_t)((ch + 2) * 64 + rr2) * H_);
            __syncthreads();
            cur ^= 1;
        }
    }
    int icol = it * 16 + ci;
    float uw = usw[icol];
    float s0 = tanhf(a0 + p2[(size_t)(2 * bgp) * H_ + icol]) * uw;
    float s1 = tanhf(a1 + p2[(size_t)(2 * bgp + 1) * H_ + icol]) * uw;
#pragma unroll
    for (int m = 1; m < 16; m <<= 1) {
        s0 += __shfl_xor(s0, m, 64);
        s1 += __shfl_xor(s1, m, 64);
    }
    if (ci == 0) {
        partial[((size_t)kt * 32 + it) * 32 + 2 * bgp] = s0;
        partial[((size_t)kt * 32 + it) * 32 + 2 * bgp + 1] = s1;
    }
}

// ---------------- Phase C: softmax + Rt + main gates GEMM + cell + out.
// Block (bt, nt): 8 batches x 64 gate-cols. K = 256 + 512 + 512.
__global__ __launch_bounds__(256) void k_phase_c(
        const float* __restrict__ emb, const float* __restrict__ h_new,
        const float* __restrict__ hm_old, float* __restrict__ hm_new,
        float* __restrict__ c_main, const float* __restrict__ partial,
        const float* __restrict__ Wx_c, const float* __restrict__ Wh_c,
        const float* __restrict__ Wm_c, const float* __restrict__ b_c,
        float* __restrict__ out, int ts) {
    __shared__ float sact[512 * PADC];    // 18,432 B
    __shared__ float swt[2][64 * 64];     // 32,768 B
    __shared__ float sg[8 * 64];
    __shared__ float ssi[8][K_];
    __shared__ float sa[8][K_];
    int blk = blockIdx.x, tid = threadIdx.x;
    int bt = blk >> 5, nt = blk & 31;
    int c = tid & 31, bg = tid >> 5;
    int l0 = 2 * c;
    int rr = tid >> 4, cc = (tid & 15) << 2;
    int wc = (l0 >> 4) * 512 + nt * 16 + (l0 & 15);
    int gcol = (cc >> 4) * 512 + nt * 16 + (cc & 15);

    // Si sums + softmax
    if (tid < 8 * K_) {
        int k = tid % K_, bl = tid / K_;
        float s = 0.f;
        for (int it = 0; it < 32; ++it)
            s += partial[((size_t)k * 32 + it) * 32 + 8 * bt + bl];
        ssi[bl][k] = s;
    }
    __syncthreads();
    if (tid < 8) {
        float m = -1e30f;
        for (int k = 0; k < K_; ++k) m = fmaxf(m, ssi[tid][k]);
        float den = 0.f, e[K_];
        for (int k = 0; k < K_; ++k) { e[k] = expf(ssi[tid][k] - m); den += e[k]; }
        float rd = 1.f / den;
        for (int k = 0; k < K_; ++k) sa[tid][k] = e[k] * rd;
    }

    const float* Wbase[3] = { Wx_c + gcol, Wh_c + gcol, Wm_c + gcol };
    int nrows[3] = { 256, 512, 512 };
    float acc0 = b_c[wc], acc1 = b_c[wc + 1];
    float4 R[4];

    for (int part = 0; part < 3; ++part) {
        if (part == 2) __syncthreads();   // redundant-safe: ensure prior compute done before Rt staging
        if (part == 0) {
            for (int idx = tid; idx < 256 * 8; idx += 256) {
                int r = idx & 255, bl = idx >> 8;
                sact[r * PADC + bl] = emb[((size_t)ts * B_ + 8 * bt + bl) * E_ + r];
            }
        } else if (part == 1) {
            for (int idx = tid; idx < 512 * 8; idx += 256) {
                int r = idx & 511, bl = idx >> 9;
                sact[r * PADC + bl] = hm_old[(size_t)(8 * bt + bl) * H_ + r];
            }
        } else {
            for (int idx = tid; idx < 512 * 8; idx += 256) {
                int r = idx & 511, bl = idx >> 9;
                float v = 0.f;
#pragma unroll
                for (int k = 0; k < K_; ++k)
                    v = fmaf(sa[bl][k], h_new[((size_t)k * B_ + 8 * bt + bl) * H_ + r], v);
                sact[r * PADC + bl] = v;
            }
        }
        const float* W = Wbase[part];
        int NC = nrows[part] >> 6;
        ld_tile64(W, G_, 0, rr, R);
        __syncthreads();
        st_tile64(swt[0], rr, cc, R);
        if (NC > 1) ld_tile64(W, G_, 64, rr, R);
        __syncthreads();
        int cur = 0;
        for (int ch = 0; ch < NC; ++ch) {
            const float* wb = swt[cur];
            const float* ab = sact + (size_t)(ch * 64) * PADC + bg;
#pragma unroll 8
            for (int r = 0; r < 64; ++r) {
                float2 w = *(const float2*)(wb + r * 64 + l0);
                float a = ab[r * PADC];
                acc0 = fmaf(w.x, a, acc0);
                acc1 = fmaf(w.y, a, acc1);
            }
            __syncthreads();
            if (ch + 1 < NC) {
                st_tile64(swt[cur ^ 1], rr, cc, R);
                if (ch + 2 < NC) ld_tile64(W, G_, (ch + 2) * 64, rr, R);
                __syncthreads();
                cur ^= 1;
            }
        }
    }

    sg[bg * 64 + l0] = acc0;
    sg[bg * 64 + l0 + 1] = acc1;
    __syncthreads();
    if (tid < 128) {
        int hc = tid & 15, bl = tid >> 4;
        int b = 8 * bt + bl;
        float gi = sg[bl * 64 + hc], gf = sg[bl * 64 + 16 + hc];
        float gg = sg[bl * 64 + 32 + hc], go = sg[bl * 64 + 48 + hc];
        size_t cidx = (size_t)b * H_ + nt * 16 + hc;
        float cold = c_main[cidx];
        float cn = sigm(gf) * cold + sigm(gi) * tanhf(gg);
        float hn = sigm(go) * tanhf(cn);
        c_main[cidx] = cn;
        hm_new[cidx] = hn;
        out[(size_t)b * S_ * H_ + (size_t)ts * H_ + nt * 16 + hc] = hn;
    }
}

__global__ void k_copy_hn(const float* __restrict__ hm, float* __restrict__ out) {
    int i = blockIdx.x * 256 + threadIdx.x;
    out[(size_t)B_ * S_ * H_ + i] = hm[i];
}

extern "C" void kernel_launch(void* const* d_in, const int* in_sizes, int n_in,
                              void* d_out, int out_size, void* d_ws, size_t ws_size,
                              hipStream_t stream) {
    const int*   x      = (const int*)d_in[0];
    const int*   taskp  = (const int*)d_in[1];
    const float* embed  = (const float*)d_in[2];
    const float* Wx_t   = (const float*)d_in[3];
    const float* Wh_t   = (const float*)d_in[4];
    const float* b_t    = (const float*)d_in[5];
    const float* Ws_p1  = (const float*)d_in[6];
    const float* Ws_p2  = (const float*)d_in[7];
    const float* Us_w   = (const float*)d_in[8];
    const float* Wx_c   = (const float*)d_in[10];
    const float* Wh_c   = (const float*)d_in[11];
    const float* Wm_c   = (const float*)d_in[12];
    const float* b_c    = (const float*)d_in[13];
    float* out = (float*)d_out;

    float* ws = (float*)d_ws;
    float* emb     = ws;                                  // S*B*E   = 4,194,304
    float* p1t     = emb     + (size_t)S_ * B_ * E_;      // H*H     =   262,144
    float* h_task  = p1t     + (size_t)H_ * H_;           // 2*K*B*H =   229,376
    float* c_task  = h_task  + 2 * (size_t)K_ * B_ * H_;  // K*B*H   =   114,688
    float* h_main  = c_task  + (size_t)K_ * B_ * H_;      // 2*B*H   =    32,768
    float* c_main  = h_main  + 2 * (size_t)B_ * H_;       // B*H     =    16,384
    float* p2      = c_main  + (size_t)B_ * H_;           // B*H     =    16,384
    float* partial = p2      + (size_t)B_ * H_;           // K*32*32 =     7,168

    int nzero = 2 * K_ * B_ * H_ + K_ * B_ * H_ + 2 * B_ * H_ + B_ * H_;
    k_zero<<<(nzero + 255) / 256, 256, 0, stream>>>(h_task, nzero);
    k_embed<<<S_ * B_, 256, 0, stream>>>(x, embed, emb);
    k_transpose_p1<<<H_ * H_ / 256, 256, 0, stream>>>(Ws_p1, p1t);

    for (int t = 0; t < S_; ++t) {
        int old = t & 1, nw = old ^ 1;
        float* ht_old = h_task + (size_t)old * K_ * B_ * H_;
        float* ht_new = h_task + (size_t)nw * K_ * B_ * H_;
        float* hm_old = h_main + (size_t)old * B_ * H_;
        float* hm_new = h_main + (size_t)nw * B_ * H_;
        k_phase_a<<<232, 256, 0, stream>>>(emb, ht_old, ht_new, c_task,
                                           Wx_t, Wh_t, b_t, taskp,
                                           hm_old, Ws_p2, p2, t);
        k_phase_b<<<224, 256, 0, stream>>>(ht_new, p2, p1t, Us_w, partial);
        k_phase_c<<<128, 256, 0, stream>>>(emb, ht_new, hm_old, hm_new, c_main,
                                           partial, Wx_c, Wh_c, Wm_c, b_c, out, t);
    }
    k_copy_hn<<<B_ * H_ / 256, 256, 0, stream>>>(h_main, out);
}